// Round 2
// baseline (1038.678 us; speedup 1.0000x reference)
//
#include <hip/hip_runtime.h>
#include <math.h>

// Problem constants (B=2, T=512 -> N=1024 tokens)
constexpr int N    = 1024;
constexpr int DIM  = 512;
constexpr int HID  = 2048;
constexpr int NE   = 64;

__device__ inline void fma4(float4& a, float s, const float4& w) {
    a.x = fmaf(s, w.x, a.x);
    a.y = fmaf(s, w.y, a.y);
    a.z = fmaf(s, w.z, a.z);
    a.w = fmaf(s, w.w, a.w);
}

// ---------------------------------------------------------------------------
// Gating: logits = (x @ emb^T)/sqrt(din); softmax; gate=max prob; idx=argmax.
// f64 accumulation so argmax matches the true argmax. 4 tokens per block.
// ---------------------------------------------------------------------------
template <int DIN>
__global__ __launch_bounds__(256) void gating_kernel(
    const float* __restrict__ X, const float* __restrict__ emb,
    float* __restrict__ gate, int* __restrict__ idx, int* __restrict__ cnt)
{
    constexpr int TPB = 4;
    const int n0  = blockIdx.x * TPB;
    const int tid = threadIdx.x;

    __shared__ float  xs[TPB][DIN];
    __shared__ double red[256];

    for (int i = tid; i < TPB * (DIN / 4); i += 256) {
        const int tk = i / (DIN / 4), j = i % (DIN / 4);
        ((float4*)xs[tk])[j] = ((const float4*)(X + (size_t)(n0 + tk) * DIN))[j];
    }
    __syncthreads();

    const int e    = tid >> 2;
    const int part = tid & 3;
    constexpr int SEG = DIN / 4;

    const float4* w4 = (const float4*)(emb + (size_t)e * DIN + part * SEG);
    double acc[TPB] = {0.0, 0.0, 0.0, 0.0};

    for (int i = 0; i < SEG / 4; i++) {
        const float4 wv = w4[i];
        #pragma unroll
        for (int tk = 0; tk < TPB; tk++) {
            const float4 xv = ((const float4*)(xs[tk] + part * SEG))[i];
            acc[tk] += (double)xv.x * (double)wv.x + (double)xv.y * (double)wv.y
                     + (double)xv.z * (double)wv.z + (double)xv.w * (double)wv.w;
        }
    }

    for (int tk = 0; tk < TPB; tk++) {
        red[tid] = acc[tk];
        __syncthreads();
        if (tid < 64) {  // wave 0
            double s = red[tid * 4] + red[tid * 4 + 1] + red[tid * 4 + 2] + red[tid * 4 + 3];
            float  l = (float)(s / sqrt((double)DIN));

            float m = l; int mi = tid;
            #pragma unroll
            for (int off = 32; off > 0; off >>= 1) {
                float om = __shfl_down(m, off);
                int   oi = __shfl_down(mi, off);
                if (om > m || (om == m && oi < mi)) { m = om; mi = oi; }
            }
            m  = __shfl(m, 0);
            mi = __shfl(mi, 0);

            float p = expf(l - m);
            float ss = p;
            #pragma unroll
            for (int off = 32; off > 0; off >>= 1) ss += __shfl_down(ss, off);

            if (tid == 0) {
                gate[n0 + tk] = 1.0f / ss;
                idx[n0 + tk]  = mi;
                atomicAdd(&cnt[mi], 1);
            }
        }
        __syncthreads();
    }
}

// ---------------------------------------------------------------------------
// Fused exclusive-scan + ranked scatter. One block, N threads.
// ---------------------------------------------------------------------------
__global__ __launch_bounds__(1024) void scan_scatter(
    const int* __restrict__ cnt, const int* __restrict__ idx,
    int* __restrict__ off, int* __restrict__ bucket)
{
    __shared__ int soff[NE];
    __shared__ int scur[NE];
    const int tid = threadIdx.x;

    if (tid == 0) {
        int s = 0;
        for (int e = 0; e < NE; e++) { soff[e] = s; off[e] = s; s += cnt[e]; }
    }
    if (tid < NE) scur[tid] = 0;
    __syncthreads();

    const int e = idx[tid];
    const int p = atomicAdd(&scur[e], 1);
    bucket[soff[e] + p] = tid;
}

// ---------------------------------------------------------------------------
// Grouped GEMM layer 1 + gate scale + exact GELU.
// grid = (NE, HID/256) = (64, 8) -> 512 blocks -> 2 blocks/CU.
// Depth-2 register prefetch on W (two 4-load batches wA/wB in flight):
// waiting on batch A overlaps consume+refill of batch B, ~550 cy slack vs
// ~900 cy HBM latency instead of the old 256 cy lockstep-vmcnt(0) pipeline.
// xs LDS reads are wave-uniform (broadcast, conflict-free); W loads are
// 1 KB/wave-instr fully coalesced.
// ---------------------------------------------------------------------------
__global__ __launch_bounds__(256, 2) void moe_gemm1(
    const float* __restrict__ X,  const float* __restrict__ W1,
    const float* __restrict__ b1, const float* __restrict__ gate,
    const int* __restrict__ cnt,  const int* __restrict__ off,
    const int* __restrict__ bucket, float* __restrict__ H)
{
    const int e    = blockIdx.x;
    const int mt   = cnt[e];
    if (mt == 0) return;
    const int base = off[e];
    const int tid  = threadIdx.x;
    const int tg   = tid >> 6;                       // token octet, wave-uniform
    const int c    = blockIdx.y * 256 + (tid & 63) * 4;

    __shared__ float xs[32][DIM];                    // 64 KB -> 2 blocks/CU

    const float* Wc = W1 + (size_t)e * DIM * HID + c;
    const float4 bias4 = *(const float4*)(b1 + (size_t)e * HID + c);

    for (int chunk = 0; chunk < mt; chunk += 32) {
        const int m = min(32, mt - chunk);

        for (int i = tid; i < m * 128; i += 256) {
            const int t = i >> 7, j = i & 127;
            ((float4*)xs[t])[j] =
                ((const float4*)(X + (size_t)bucket[base + chunk + t] * DIM))[j];
        }
        __syncthreads();

        float4 acc[8];
        #pragma unroll
        for (int t = 0; t < 8; t++) acc[t] = make_float4(0.f, 0.f, 0.f, 0.f);

        // depth-2 software pipeline: batches A (dg) and B (dg+1) in flight
        float4 wA[4], wB[4];
        #pragma unroll
        for (int r = 0; r < 4; r++) wA[r] = *(const float4*)(Wc + (size_t)r * HID);
        #pragma unroll
        for (int r = 0; r < 4; r++) wB[r] = *(const float4*)(Wc + (size_t)(4 + r) * HID);

        for (int dg = 0; dg < 128; dg += 2) {
            #pragma unroll
            for (int t = 0; t < 8; t++) {
                const float4 xv = *(const float4*)&xs[tg * 8 + t][dg * 4];
                fma4(acc[t], xv.x, wA[0]);
                fma4(acc[t], xv.y, wA[1]);
                fma4(acc[t], xv.z, wA[2]);
                fma4(acc[t], xv.w, wA[3]);
            }
            if (dg + 2 < 128) {
                const float* wq = Wc + (size_t)(dg + 2) * 4 * HID;
                #pragma unroll
                for (int r = 0; r < 4; r++) wA[r] = *(const float4*)(wq + (size_t)r * HID);
            }
            #pragma unroll
            for (int t = 0; t < 8; t++) {
                const float4 xv = *(const float4*)&xs[tg * 8 + t][dg * 4 + 4];
                fma4(acc[t], xv.x, wB[0]);
                fma4(acc[t], xv.y, wB[1]);
                fma4(acc[t], xv.z, wB[2]);
                fma4(acc[t], xv.w, wB[3]);
            }
            if (dg + 3 < 128) {
                const float* wq = Wc + (size_t)(dg + 3) * 4 * HID;
                #pragma unroll
                for (int r = 0; r < 4; r++) wB[r] = *(const float4*)(wq + (size_t)r * HID);
            }
        }

        #pragma unroll
        for (int t = 0; t < 8; t++) {
            const int ti = chunk + tg * 8 + t;
            if (ti < mt) {
                const int   tok = bucket[base + ti];
                const float g   = gate[tok];
                float4 v;
                v.x = g * (acc[t].x + bias4.x);
                v.y = g * (acc[t].y + bias4.y);
                v.z = g * (acc[t].z + bias4.z);
                v.w = g * (acc[t].w + bias4.w);
                v.x = 0.5f * v.x * (1.0f + erff(v.x * 0.70710678118654752f));
                v.y = 0.5f * v.y * (1.0f + erff(v.y * 0.70710678118654752f));
                v.z = 0.5f * v.z * (1.0f + erff(v.z * 0.70710678118654752f));
                v.w = 0.5f * v.w * (1.0f + erff(v.w * 0.70710678118654752f));
                *(float4*)(H + (size_t)tok * HID + c) = v;
            }
        }
        __syncthreads();
    }
}

// ---------------------------------------------------------------------------
// Grouped GEMM layer 2 + gate scale. grid = (NE, DIM/256, 8 K-slices)
// = (64, 2, 8) -> 1024 blocks. K-slice = 256 rows -> xs is 32 KB ->
// 4 blocks/CU (16 waves/CU, 4 waves/SIMD) with __launch_bounds__(256,4).
// Depth-2 W prefetch as in gemm1. Partials combined via atomicAdd.
// ---------------------------------------------------------------------------
__global__ __launch_bounds__(256, 4) void moe_gemm2(
    const float* __restrict__ Hm, const float* __restrict__ W2,
    const float* __restrict__ b2, const float* __restrict__ gate,
    const int* __restrict__ cnt,  const int* __restrict__ off,
    const int* __restrict__ bucket, float* __restrict__ out)
{
    const int e    = blockIdx.x;
    const int z    = blockIdx.z;                     // K-slice, 256 rows each
    const int mt   = cnt[e];
    if (mt == 0) return;
    const int base = off[e];
    const int tid  = threadIdx.x;
    const int tg   = tid >> 6;                       // token octet, wave-uniform
    const int c    = blockIdx.y * 256 + (tid & 63) * 4;

    __shared__ float xs[32][256];                    // 32 KB -> 4 blocks/CU

    const float* Wc = W2 + (size_t)e * HID * DIM + (size_t)z * 256 * DIM + c;
    float4 bias4 = make_float4(0.f, 0.f, 0.f, 0.f);
    if (z == 0) bias4 = *(const float4*)(b2 + (size_t)e * DIM + c);

    for (int chunk = 0; chunk < mt; chunk += 32) {
        const int m = min(32, mt - chunk);

        for (int i = tid; i < m * 64; i += 256) {
            const int t = i >> 6, j = i & 63;
            ((float4*)xs[t])[j] =
                ((const float4*)(Hm + (size_t)bucket[base + chunk + t] * HID + z * 256))[j];
        }
        __syncthreads();

        float4 acc[8];
        #pragma unroll
        for (int t = 0; t < 8; t++) acc[t] = make_float4(0.f, 0.f, 0.f, 0.f);

        float4 wA[4], wB[4];
        #pragma unroll
        for (int r = 0; r < 4; r++) wA[r] = *(const float4*)(Wc + (size_t)r * DIM);
        #pragma unroll
        for (int r = 0; r < 4; r++) wB[r] = *(const float4*)(Wc + (size_t)(4 + r) * DIM);

        for (int dg = 0; dg < 64; dg += 2) {
            #pragma unroll
            for (int t = 0; t < 8; t++) {
                const float4 xv = *(const float4*)&xs[tg * 8 + t][dg * 4];
                fma4(acc[t], xv.x, wA[0]);
                fma4(acc[t], xv.y, wA[1]);
                fma4(acc[t], xv.z, wA[2]);
                fma4(acc[t], xv.w, wA[3]);
            }
            if (dg + 2 < 64) {
                const float* wq = Wc + (size_t)(dg + 2) * 4 * DIM;
                #pragma unroll
                for (int r = 0; r < 4; r++) wA[r] = *(const float4*)(wq + (size_t)r * DIM);
            }
            #pragma unroll
            for (int t = 0; t < 8; t++) {
                const float4 xv = *(const float4*)&xs[tg * 8 + t][dg * 4 + 4];
                fma4(acc[t], xv.x, wB[0]);
                fma4(acc[t], xv.y, wB[1]);
                fma4(acc[t], xv.z, wB[2]);
                fma4(acc[t], xv.w, wB[3]);
            }
            if (dg + 3 < 64) {
                const float* wq = Wc + (size_t)(dg + 3) * 4 * DIM;
                #pragma unroll
                for (int r = 0; r < 4; r++) wB[r] = *(const float4*)(wq + (size_t)r * DIM);
            }
        }

        #pragma unroll
        for (int t = 0; t < 8; t++) {
            const int ti = chunk + tg * 8 + t;
            if (ti < mt) {
                const int   tok = bucket[base + ti];
                const float g   = gate[tok];
                float* o = out + (size_t)tok * DIM + c;
                atomicAdd(o + 0, g * (acc[t].x + bias4.x));
                atomicAdd(o + 1, g * (acc[t].y + bias4.y));
                atomicAdd(o + 2, g * (acc[t].z + bias4.z));
                atomicAdd(o + 3, g * (acc[t].w + bias4.w));
            }
        }
        __syncthreads();
    }
}

// ---------------------------------------------------------------------------
extern "C" void kernel_launch(void* const* d_in, const int* in_sizes, int n_in,
                              void* d_out, int out_size, void* d_ws, size_t ws_size,
                              hipStream_t stream)
{
    const float* x    = (const float*)d_in[0];
    const float* emb1 = (const float*)d_in[1];
    const float* W1   = (const float*)d_in[2];
    const float* b1   = (const float*)d_in[3];
    const float* emb2 = (const float*)d_in[4];
    const float* W2   = (const float*)d_in[5];
    const float* b2   = (const float*)d_in[6];
    float* out = (float*)d_out;

    // workspace layout (~8.03 MB)
    float* H       = (float*)d_ws;              // N*HID
    float* gate1   = H + (size_t)N * HID;       // N
    float* gate2   = gate1 + N;                 // N
    int*   idx1    = (int*)(gate2 + N);         // N
    int*   idx2    = idx1 + N;                  // N
    int*   bucket1 = idx2 + N;                  // N
    int*   bucket2 = bucket1 + N;               // N
    int*   cnt1    = bucket2 + N;               // 4*NE contiguous ints below
    int*   off1    = cnt1 + NE;
    int*   cnt2    = off1 + NE;
    int*   off2    = cnt2 + NE;

    hipMemsetAsync(cnt1, 0, 4 * NE * sizeof(int), stream);
    hipMemsetAsync(out, 0, (size_t)N * DIM * sizeof(float), stream);

    // layer 1
    gating_kernel<DIM><<<N / 4, 256, 0, stream>>>(x, emb1, gate1, idx1, cnt1);
    scan_scatter<<<1, N, 0, stream>>>(cnt1, idx1, off1, bucket1);
    moe_gemm1<<<dim3(NE, HID / 256), 256, 0, stream>>>(x, W1, b1, gate1, cnt1, off1,
                                                       bucket1, H);
    // layer 2
    gating_kernel<HID><<<N / 4, 256, 0, stream>>>(H, emb2, gate2, idx2, cnt2);
    scan_scatter<<<1, N, 0, stream>>>(cnt2, idx2, off2, bucket2);
    moe_gemm2<<<dim3(NE, DIM / 256, 8), 256, 0, stream>>>(H, W2, b2, gate2, cnt2, off2,
                                                          bucket2, out);
}

// Round 3
// 678.346 us; speedup vs baseline: 1.5312x; 1.5312x over previous
//
#include <hip/hip_runtime.h>
#include <math.h>

// Problem constants (B=2, T=512 -> N=1024 tokens)
constexpr int N    = 1024;
constexpr int DIM  = 512;
constexpr int HID  = 2048;
constexpr int NE   = 64;

__device__ inline void fma4(float4& a, float s, const float4& w) {
    a.x = fmaf(s, w.x, a.x);
    a.y = fmaf(s, w.y, a.y);
    a.z = fmaf(s, w.z, a.z);
    a.w = fmaf(s, w.w, a.w);
}

// ---------------------------------------------------------------------------
// Gating: logits = (x @ emb^T)/sqrt(din); softmax; gate=max prob; idx=argmax.
// f64 accumulation so argmax matches the true argmax. 4 tokens per block.
// ---------------------------------------------------------------------------
template <int DIN>
__global__ __launch_bounds__(256) void gating_kernel(
    const float* __restrict__ X, const float* __restrict__ emb,
    float* __restrict__ gate, int* __restrict__ idx, int* __restrict__ cnt)
{
    constexpr int TPB = 4;
    const int n0  = blockIdx.x * TPB;
    const int tid = threadIdx.x;

    __shared__ float  xs[TPB][DIN];
    __shared__ double red[256];

    for (int i = tid; i < TPB * (DIN / 4); i += 256) {
        const int tk = i / (DIN / 4), j = i % (DIN / 4);
        ((float4*)xs[tk])[j] = ((const float4*)(X + (size_t)(n0 + tk) * DIN))[j];
    }
    __syncthreads();

    const int e    = tid >> 2;
    const int part = tid & 3;
    constexpr int SEG = DIN / 4;

    const float4* w4 = (const float4*)(emb + (size_t)e * DIN + part * SEG);
    double acc[TPB] = {0.0, 0.0, 0.0, 0.0};

    for (int i = 0; i < SEG / 4; i++) {
        const float4 wv = w4[i];
        #pragma unroll
        for (int tk = 0; tk < TPB; tk++) {
            const float4 xv = ((const float4*)(xs[tk] + part * SEG))[i];
            acc[tk] += (double)xv.x * (double)wv.x + (double)xv.y * (double)wv.y
                     + (double)xv.z * (double)wv.z + (double)xv.w * (double)wv.w;
        }
    }

    for (int tk = 0; tk < TPB; tk++) {
        red[tid] = acc[tk];
        __syncthreads();
        if (tid < 64) {  // wave 0
            double s = red[tid * 4] + red[tid * 4 + 1] + red[tid * 4 + 2] + red[tid * 4 + 3];
            float  l = (float)(s / sqrt((double)DIN));

            float m = l; int mi = tid;
            #pragma unroll
            for (int off = 32; off > 0; off >>= 1) {
                float om = __shfl_down(m, off);
                int   oi = __shfl_down(mi, off);
                if (om > m || (om == m && oi < mi)) { m = om; mi = oi; }
            }
            m  = __shfl(m, 0);
            mi = __shfl(mi, 0);

            float p = expf(l - m);
            float ss = p;
            #pragma unroll
            for (int off = 32; off > 0; off >>= 1) ss += __shfl_down(ss, off);

            if (tid == 0) {
                gate[n0 + tk] = 1.0f / ss;
                idx[n0 + tk]  = mi;
                atomicAdd(&cnt[mi], 1);
            }
        }
        __syncthreads();
    }
}

// ---------------------------------------------------------------------------
// Fused exclusive-scan + ranked scatter. One block, N threads.
// ---------------------------------------------------------------------------
__global__ __launch_bounds__(1024) void scan_scatter(
    const int* __restrict__ cnt, const int* __restrict__ idx,
    int* __restrict__ off, int* __restrict__ bucket)
{
    __shared__ int soff[NE];
    __shared__ int scur[NE];
    const int tid = threadIdx.x;

    if (tid == 0) {
        int s = 0;
        for (int e = 0; e < NE; e++) { soff[e] = s; off[e] = s; s += cnt[e]; }
    }
    if (tid < NE) scur[tid] = 0;
    __syncthreads();

    const int e = idx[tid];
    const int p = atomicAdd(&scur[e], 1);
    bucket[soff[e] + p] = tid;
}

// ---------------------------------------------------------------------------
// Grouped GEMM layer 1 + gate scale + exact GELU. NO cross-block K-split.
// grid = (NE, DIM_col_blocks=16) = 1024 blocks -> 4 blocks/CU (32 KB LDS).
// Lane map: q = l&31 -> 4 cols of the block's 128; rp = l>>5 -> K-row parity.
// Wave w owns tokens w*8..w*8+7 (acc float4[8]); full K accumulated in regs
// over 2 LDS K-chunks, then one shfl_xor(32) reduce + plain store. W1 read
// exactly once grid-wide; per-instr W loads = 2x512B contiguous segments.
// ---------------------------------------------------------------------------
__global__ __launch_bounds__(256, 4) void moe_gemm1(
    const float* __restrict__ X,  const float* __restrict__ W1,
    const float* __restrict__ b1, const float* __restrict__ gate,
    const int* __restrict__ cnt,  const int* __restrict__ off,
    const int* __restrict__ bucket, float* __restrict__ H)
{
    const int e    = blockIdx.x;
    const int mt   = cnt[e];
    if (mt == 0) return;
    const int base = off[e];
    const int cb   = blockIdx.y;
    const int tid  = threadIdx.x;
    const int wv   = tid >> 6;          // wave -> token octet
    const int l    = tid & 63;
    const int q    = l & 31;            // col quad
    const int rp   = l >> 5;            // K-row parity (0/1)

    __shared__ float xs[32][256];       // 32 KB -> 4 blocks/CU

    const int cq = cb * 128 + q * 4;
    const float* Wb = W1 + (size_t)e * DIM * HID + cq;
    const float4 bias4 = *(const float4*)(b1 + (size_t)e * HID + cq);

    for (int chunk = 0; chunk < mt; chunk += 32) {
        const int m = min(32, mt - chunk);

        float4 acc[8];
        #pragma unroll
        for (int t = 0; t < 8; t++) acc[t] = make_float4(0.f, 0.f, 0.f, 0.f);

        for (int kc = 0; kc < 2; kc++) {
            for (int i = tid; i < m * 64; i += 256) {
                const int t = i >> 6, j = i & 63;
                ((float4*)xs[t])[j] =
                    ((const float4*)(X + (size_t)bucket[base + chunk + t] * DIM + kc * 256))[j];
            }
            __syncthreads();

            // rows covered this chunk: kc*256 + dg*2 + rp, dg in [0,128)
            const float* Wk = Wb + (size_t)(kc * 256 + rp) * HID;
            float4 wA = *(const float4*)(Wk + (size_t)0 * 2 * HID);
            float4 wB = *(const float4*)(Wk + (size_t)1 * 2 * HID);
            float4 wC = *(const float4*)(Wk + (size_t)2 * 2 * HID);
            float4 wD = *(const float4*)(Wk + (size_t)3 * 2 * HID);

            for (int dg = 0; dg < 128; dg += 4) {
                #pragma unroll
                for (int t = 0; t < 8; t++)
                    fma4(acc[t], xs[wv * 8 + t][(dg + 0) * 2 + rp], wA);
                if (dg + 4 < 128) wA = *(const float4*)(Wk + (size_t)(dg + 4) * 2 * HID);
                #pragma unroll
                for (int t = 0; t < 8; t++)
                    fma4(acc[t], xs[wv * 8 + t][(dg + 1) * 2 + rp], wB);
                if (dg + 5 < 128) wB = *(const float4*)(Wk + (size_t)(dg + 5) * 2 * HID);
                #pragma unroll
                for (int t = 0; t < 8; t++)
                    fma4(acc[t], xs[wv * 8 + t][(dg + 2) * 2 + rp], wC);
                if (dg + 6 < 128) wC = *(const float4*)(Wk + (size_t)(dg + 6) * 2 * HID);
                #pragma unroll
                for (int t = 0; t < 8; t++)
                    fma4(acc[t], xs[wv * 8 + t][(dg + 3) * 2 + rp], wD);
                if (dg + 7 < 128) wD = *(const float4*)(Wk + (size_t)(dg + 7) * 2 * HID);
            }
            __syncthreads();
        }

        // reduce the two K-row parities (lanes l and l^32)
        #pragma unroll
        for (int t = 0; t < 8; t++) {
            acc[t].x += __shfl_xor(acc[t].x, 32);
            acc[t].y += __shfl_xor(acc[t].y, 32);
            acc[t].z += __shfl_xor(acc[t].z, 32);
            acc[t].w += __shfl_xor(acc[t].w, 32);
        }

        if (rp == 0) {
            #pragma unroll
            for (int t = 0; t < 8; t++) {
                const int ti = chunk + wv * 8 + t;
                if (ti < mt) {
                    const int   tok = bucket[base + ti];
                    const float g   = gate[tok];
                    float4 v;
                    v.x = g * (acc[t].x + bias4.x);
                    v.y = g * (acc[t].y + bias4.y);
                    v.z = g * (acc[t].z + bias4.z);
                    v.w = g * (acc[t].w + bias4.w);
                    v.x = 0.5f * v.x * (1.0f + erff(v.x * 0.70710678118654752f));
                    v.y = 0.5f * v.y * (1.0f + erff(v.y * 0.70710678118654752f));
                    v.z = 0.5f * v.z * (1.0f + erff(v.z * 0.70710678118654752f));
                    v.w = 0.5f * v.w * (1.0f + erff(v.w * 0.70710678118654752f));
                    *(float4*)(H + (size_t)tok * HID + cq) = v;
                }
            }
        }
    }
}

// ---------------------------------------------------------------------------
// Grouped GEMM layer 2 + gate scale. NO K-split atomics (round-2 showed 8.4M
// device-scope atomics generating 1.29 GB of HBM write RMW traffic = 524 us).
// grid = (NE, 16 col-blocks of 32 cols) = 1024 blocks -> 4 blocks/CU.
// Lane map: q = l&7 (col quad), p = l>>3 (K-row phase 0..7). Full K=2048
// accumulated in registers over 8 LDS chunks of 256 rows; epilogue = 3
// shfl_xor rounds + one plain float4 store. out written exactly once.
// ---------------------------------------------------------------------------
__global__ __launch_bounds__(256, 4) void moe_gemm2(
    const float* __restrict__ Hm, const float* __restrict__ W2,
    const float* __restrict__ b2, const float* __restrict__ gate,
    const int* __restrict__ cnt,  const int* __restrict__ off,
    const int* __restrict__ bucket, float* __restrict__ out)
{
    const int e    = blockIdx.x;
    const int mt   = cnt[e];
    if (mt == 0) return;
    const int base = off[e];
    const int cb   = blockIdx.y;
    const int tid  = threadIdx.x;
    const int wv   = tid >> 6;          // wave -> token octet
    const int l    = tid & 63;
    const int q    = l & 7;             // col quad (8 quads = 32 cols)
    const int p    = l >> 3;            // K-row phase (0..7)

    __shared__ float xs[32][256];       // 32 KB -> 4 blocks/CU

    const int cq = cb * 32 + q * 4;
    const float* Wb = W2 + (size_t)e * HID * DIM + cq;
    const float4 bias4 = *(const float4*)(b2 + (size_t)e * DIM + cq);

    for (int chunk = 0; chunk < mt; chunk += 32) {
        const int m = min(32, mt - chunk);

        float4 acc[8];
        #pragma unroll
        for (int t = 0; t < 8; t++) acc[t] = make_float4(0.f, 0.f, 0.f, 0.f);

        for (int kc = 0; kc < 8; kc++) {
            for (int i = tid; i < m * 64; i += 256) {
                const int t = i >> 6, j = i & 63;
                ((float4*)xs[t])[j] =
                    ((const float4*)(Hm + (size_t)bucket[base + chunk + t] * HID + kc * 256))[j];
            }
            __syncthreads();

            // rows covered this chunk: kc*256 + dg*8 + p, dg in [0,32)
            const float* Wk = Wb + (size_t)(kc * 256 + p) * DIM;
            float4 wA = *(const float4*)(Wk + (size_t)0 * 8 * DIM);
            float4 wB = *(const float4*)(Wk + (size_t)1 * 8 * DIM);
            float4 wC = *(const float4*)(Wk + (size_t)2 * 8 * DIM);
            float4 wD = *(const float4*)(Wk + (size_t)3 * 8 * DIM);

            for (int dg = 0; dg < 32; dg += 4) {
                #pragma unroll
                for (int t = 0; t < 8; t++)
                    fma4(acc[t], xs[wv * 8 + t][(dg + 0) * 8 + p], wA);
                if (dg + 4 < 32) wA = *(const float4*)(Wk + (size_t)(dg + 4) * 8 * DIM);
                #pragma unroll
                for (int t = 0; t < 8; t++)
                    fma4(acc[t], xs[wv * 8 + t][(dg + 1) * 8 + p], wB);
                if (dg + 5 < 32) wB = *(const float4*)(Wk + (size_t)(dg + 5) * 8 * DIM);
                #pragma unroll
                for (int t = 0; t < 8; t++)
                    fma4(acc[t], xs[wv * 8 + t][(dg + 2) * 8 + p], wC);
                if (dg + 6 < 32) wC = *(const float4*)(Wk + (size_t)(dg + 6) * 8 * DIM);
                #pragma unroll
                for (int t = 0; t < 8; t++)
                    fma4(acc[t], xs[wv * 8 + t][(dg + 3) * 8 + p], wD);
                if (dg + 7 < 32) wD = *(const float4*)(Wk + (size_t)(dg + 7) * 8 * DIM);
            }
            __syncthreads();
        }

        // reduce the 8 K-row phases (xor 8, 16, 32 within the wave)
        #pragma unroll
        for (int t = 0; t < 8; t++) {
            #pragma unroll
            for (int mk = 8; mk <= 32; mk <<= 1) {
                acc[t].x += __shfl_xor(acc[t].x, mk);
                acc[t].y += __shfl_xor(acc[t].y, mk);
                acc[t].z += __shfl_xor(acc[t].z, mk);
                acc[t].w += __shfl_xor(acc[t].w, mk);
            }
        }

        if (p == 0) {
            #pragma unroll
            for (int t = 0; t < 8; t++) {
                const int ti = chunk + wv * 8 + t;
                if (ti < mt) {
                    const int   tok = bucket[base + ti];
                    const float g   = gate[tok];
                    float4 v;
                    v.x = g * (acc[t].x + bias4.x);
                    v.y = g * (acc[t].y + bias4.y);
                    v.z = g * (acc[t].z + bias4.z);
                    v.w = g * (acc[t].w + bias4.w);
                    *(float4*)(out + (size_t)tok * DIM + cq) = v;
                }
            }
        }
    }
}

// ---------------------------------------------------------------------------
extern "C" void kernel_launch(void* const* d_in, const int* in_sizes, int n_in,
                              void* d_out, int out_size, void* d_ws, size_t ws_size,
                              hipStream_t stream)
{
    const float* x    = (const float*)d_in[0];
    const float* emb1 = (const float*)d_in[1];
    const float* W1   = (const float*)d_in[2];
    const float* b1   = (const float*)d_in[3];
    const float* emb2 = (const float*)d_in[4];
    const float* W2   = (const float*)d_in[5];
    const float* b2   = (const float*)d_in[6];
    float* out = (float*)d_out;

    // workspace layout (~8.03 MB)
    float* H       = (float*)d_ws;              // N*HID
    float* gate1   = H + (size_t)N * HID;       // N
    float* gate2   = gate1 + N;                 // N
    int*   idx1    = (int*)(gate2 + N);         // N
    int*   idx2    = idx1 + N;                  // N
    int*   bucket1 = idx2 + N;                  // N
    int*   bucket2 = bucket1 + N;               // N
    int*   cnt1    = bucket2 + N;               // 4*NE contiguous ints below
    int*   off1    = cnt1 + NE;
    int*   cnt2    = off1 + NE;
    int*   off2    = cnt2 + NE;

    hipMemsetAsync(cnt1, 0, 4 * NE * sizeof(int), stream);

    // layer 1
    gating_kernel<DIM><<<N / 4, 256, 0, stream>>>(x, emb1, gate1, idx1, cnt1);
    scan_scatter<<<1, N, 0, stream>>>(cnt1, idx1, off1, bucket1);
    moe_gemm1<<<dim3(NE, 16), 256, 0, stream>>>(x, W1, b1, gate1, cnt1, off1,
                                                bucket1, H);
    // layer 2
    gating_kernel<HID><<<N / 4, 256, 0, stream>>>(H, emb2, gate2, idx2, cnt2);
    scan_scatter<<<1, N, 0, stream>>>(cnt2, idx2, off2, bucket2);
    moe_gemm2<<<dim3(NE, 16), 256, 0, stream>>>(H, W2, b2, gate2, cnt2, off2,
                                                bucket2, out);
}